// Round 1
// 1173.907 us; speedup vs baseline: 1.8487x; 1.8487x over previous
//
#include <hip/hip_runtime.h>
#include <cmath>

// Problem constants (from reference setup_inputs)
#define B       64
#define IN_PN   20000
#define OUT_PN  5000
#define MM      9
#define CIN     32
#define COUT    64
#define XS_STRIDE  36   // 32 + 4 pad: bank-friendly lane-distinct b128 LDS reads
#define OUT_STRIDE 68   // 64 + 4 pad for epilogue transpose

typedef __attribute__((ext_vector_type(4))) float f32x4;
// Constant-address-space views: uniform-address loads select s_load_* through K$.
typedef __attribute__((address_space(4))) const float  AS4f;
typedef __attribute__((address_space(4))) const f32x4  AS4f4;

// One block per output point p. 256 threads = 4 waves.
// Compute map: b = tid&63 (batch lane), og = wave id (16 outputs each).
// W / bias / weight_res are wave-uniform -> scalar pipe (SGPRs), NOT LDS.
// X gather double-buffered in LDS: one __syncthreads per m-iteration,
// next-m gather issued as plain global->VGPR loads that ride across the barrier.
__global__ __launch_bounds__(256, 4) void pconv_kernel(
    const float* __restrict__ in_pc,       // (B, IN_PN, CIN)
    const int*   __restrict__ neighbor_id, // (OUT_PN, M)
    const float* __restrict__ weights,     // (OUT_PN, M, COUT, CIN)
    const float* __restrict__ bias,        // (OUT_PN, COUT)
    const float* __restrict__ p_neighbors, // (OUT_PN, M)
    const float* __restrict__ weight_res,  // (COUT, CIN)
    float*       __restrict__ out)         // (B, OUT_PN, COUT)
{
    __shared__ float smem[2 * 64 * XS_STRIDE]; // 4608 floats = 18432 B (dbuf X; epilogue overlay 64x68=4352)
    const int p  = blockIdx.x;
    const int t  = threadIdx.x;
    const int b  = t & 63;   // compute: batch row
    const int og = __builtin_amdgcn_readfirstlane(t >> 6); // wave-uniform output group
    const int bb = t >> 2;   // staging: row
    const int q  = t & 3;    // staging: quarter of a 32-float row

    // ---- neighbor ids + normalized residual weights (block-uniform) ----
    int   nid[MM];
    float pn[MM];
    float psum = 0.f;
#pragma unroll
    for (int m = 0; m < MM; ++m) {
        nid[m] = neighbor_id[p * MM + m];
        float pv = fabsf(p_neighbors[p * MM + m]);
        pv = (nid[m] != IN_PN) ? pv : 0.f;
        pn[m] = pv;
        psum += pv;
    }
    const float pinv = 1.f / (psum + 1e-8f);
#pragma unroll
    for (int m = 0; m < MM; ++m) pn[m] *= pinv;

    // ---- wave-uniform scalar pointers (constant AS -> s_load via K$) ----
    const AS4f4* Wp = (const AS4f4*)(uintptr_t)weights
                    + (size_t)p * (MM * COUT * CIN / 4) + og * (16 * CIN / 4);
    const AS4f4* WR = (const AS4f4*)(uintptr_t)weight_res + og * (16 * CIN / 4);
    const AS4f*  bi = (const AS4f*)(uintptr_t)bias + p * COUT + og * 16;

    float acc[16];
#pragma unroll
    for (int j = 0; j < 16; ++j) acc[j] = 0.f;
    float rv[8];
#pragma unroll
    for (int i = 0; i < 8; ++i) rv[i] = 0.f;

    // ---- prefetch X gather for m=0 (plain loads into VGPRs) ----
    float4 a0, a1;
    {
        const int n = nid[0];
        if (n != IN_PN) {
            const float* src = in_pc + ((size_t)bb * IN_PN + (size_t)n) * CIN;
            a0 = *(const float4*)(src + q * 4);
            a1 = *(const float4*)(src + 16 + q * 4);
        } else {
            a0 = make_float4(0.f, 0.f, 0.f, 0.f); a1 = a0;
        }
    }

    // ---- main m-loop: one sync per iteration (double-buffered X tile) ----
    for (int m = 0; m < MM; ++m) {
        float* Xs = smem + (m & 1) * (64 * XS_STRIDE);
        *(float4*)&Xs[bb * XS_STRIDE + q * 4]      = a0;
        *(float4*)&Xs[bb * XS_STRIDE + 16 + q * 4] = a1;

        if (m + 1 < MM) {  // issue next gather; latency hides under the FMA tile
            const int n = nid[m + 1];
            if (n != IN_PN) {
                const float* src = in_pc + ((size_t)bb * IN_PN + (size_t)n) * CIN;
                a0 = *(const float4*)(src + q * 4);
                a1 = *(const float4*)(src + 16 + q * 4);
            } else {
                a0 = make_float4(0.f, 0.f, 0.f, 0.f); a1 = a0;
            }
        }
        __syncthreads();

        float4 xv[8];
#pragma unroll
        for (int c4 = 0; c4 < 8; ++c4)
            xv[c4] = *(const float4*)&Xs[b * XS_STRIDE + c4 * 4];

        // residual accumulation: this thread owns c = og*8..og*8+7
        // (re-read from LDS with a uniform og offset — avoids runtime-indexed
        //  register arrays, rule #20)
        const float pm = pn[m];
        {
            float4 x0 = *(const float4*)&Xs[b * XS_STRIDE + og * 8];
            float4 x1 = *(const float4*)&Xs[b * XS_STRIDE + og * 8 + 4];
            rv[0] += pm * x0.x; rv[1] += pm * x0.y;
            rv[2] += pm * x0.z; rv[3] += pm * x0.w;
            rv[4] += pm * x1.x; rv[5] += pm * x1.y;
            rv[6] += pm * x1.z; rv[7] += pm * x1.w;
        }

        const AS4f4* Wm = Wp + m * (COUT * CIN / 4);
#pragma unroll
        for (int j = 0; j < 16; ++j) {
            float s = acc[j];
#pragma unroll
            for (int c4 = 0; c4 < 8; ++c4) {
                f32x4 w = Wm[j * 8 + c4];        // s_load_dwordx4 (wave-uniform)
                s += xv[c4].x * w.x;
                s += xv[c4].y * w.y;
                s += xv[c4].z * w.z;
                s += xv[c4].w * w.w;
            }
            acc[j] = s;
        }
        // no trailing sync: buffer (m&1) is next written at m+2, after sync(m+1)
    }

    // ---- residual GEMM: Rs(64x32) . weight_res(64x32)^T via scalar W ----
    // stage rv into buf1 (last read at m=7; all threads are past sync(m=8))
    float* Rs = smem + 64 * XS_STRIDE;
    *(float4*)&Rs[b * XS_STRIDE + og * 8]     = make_float4(rv[0], rv[1], rv[2], rv[3]);
    *(float4*)&Rs[b * XS_STRIDE + og * 8 + 4] = make_float4(rv[4], rv[5], rv[6], rv[7]);
    __syncthreads();

    float4 xr[8];
#pragma unroll
    for (int c4 = 0; c4 < 8; ++c4)
        xr[c4] = *(const float4*)&Rs[b * XS_STRIDE + c4 * 4];

    float outv[16];
#pragma unroll
    for (int j = 0; j < 16; ++j) {
        float r = 0.f;
#pragma unroll
        for (int c4 = 0; c4 < 8; ++c4) {
            f32x4 w = WR[j * 8 + c4];            // s_load (uniform)
            r += xr[c4].x * w.x + xr[c4].y * w.y + xr[c4].z * w.z + xr[c4].w * w.w;
        }
        float cv = acc[j] + bi[j];               // scalar bias load
        cv = (cv > 0.f) ? cv : expm1f(cv);       // jax.nn.elu
        outv[j] = 0.70710678118654752f * (cv + r); // sqrt(1-RR) == sqrt(RR)
    }
    __syncthreads(); // all reads of Rs done; smem becomes the transpose buffer

    // ---- epilogue transpose for coalesced 256B-contiguous stores ----
#pragma unroll
    for (int j = 0; j < 16; ++j)
        smem[b * OUT_STRIDE + og * 16 + j] = outv[j];
    __syncthreads();

#pragma unroll
    for (int s = 0; s < 4; ++s) {
        float4 v = *(const float4*)&smem[bb * OUT_STRIDE + q * 16 + s * 4];
        *(float4*)&out[((size_t)bb * OUT_PN + (size_t)p) * COUT + q * 16 + s * 4] = v;
    }
}

extern "C" void kernel_launch(void* const* d_in, const int* in_sizes, int n_in,
                              void* d_out, int out_size, void* d_ws, size_t ws_size,
                              hipStream_t stream) {
    const float* in_pc       = (const float*)d_in[0];
    const int*   neighbor_id = (const int*)d_in[1];
    const float* weights     = (const float*)d_in[2];
    const float* bias        = (const float*)d_in[3];
    const float* p_neighbors = (const float*)d_in[4];
    const float* weight_res  = (const float*)d_in[5];
    float*       out         = (float*)d_out;

    pconv_kernel<<<OUT_PN, 256, 0, stream>>>(in_pc, neighbor_id, weights, bias,
                                             p_neighbors, weight_res, out);
}

// Round 2
// 761.659 us; speedup vs baseline: 2.8493x; 1.5412x over previous
//
#include <hip/hip_runtime.h>
#include <cmath>

// Problem constants (from reference setup_inputs)
#define IN_PN   20000
#define OUT_PN  5000
#define MM      9
#define CIN     32
#define COUT    64

typedef short        bf16x8 __attribute__((ext_vector_type(8)));
typedef float        f32x16 __attribute__((ext_vector_type(16)));
typedef unsigned int u32x4  __attribute__((ext_vector_type(4)));

// Pack [bf16(x1) : bf16(x0)] by truncation (RTZ). The lo-part of the split
// captures the truncation remainder exactly (x - trunc(x) is exact in fp32).
__device__ __forceinline__ unsigned pack_bf16_hi(float x0, float x1) {
    return __builtin_amdgcn_perm(__float_as_uint(x1), __float_as_uint(x0), 0x07060302u);
}
__device__ __forceinline__ float bf16_trunc(float x) {
    return __uint_as_float(__float_as_uint(x) & 0xFFFF0000u);
}
__device__ __forceinline__ bf16x8 frag(u32x4 u) {
    return __builtin_bit_cast(bf16x8, u);
}
// Split 8 consecutive fp32 into hi/lo bf16 fragments (4 VGPRs each).
__device__ __forceinline__ void split8(const float* x, u32x4& hi, u32x4& lo) {
#pragma unroll
    for (int i = 0; i < 4; ++i) {
        float x0 = x[2 * i], x1 = x[2 * i + 1];
        hi[i] = pack_bf16_hi(x0, x1);
        lo[i] = pack_bf16_hi(x0 - bf16_trunc(x0), x1 - bf16_trunc(x1));
    }
}

// One block per output point p; 4 waves; wave (wr,wc) owns C tile [wr*32..][wc*32..].
// Per block: C(64x64) = X(64x288) . W(288x64) via v_mfma_f32_32x32x16_bf16 with
// 3-product hi/lo split (fp32-grade precision). No LDS, no barriers: both operands
// stream straight from global into MFMA fragments.
//   A-fragment (32x32x16): row = lane%32, k = (lane/32)*8 + e   (e = elem 0..7)
//   B-fragment:            col = lane%32, k = (lane/32)*8 + e
//   C/D (HW-verified):     col = lane&31, row = (reg&3) + 8*(reg>>2) + 4*(lane>>5)
// Residual path: rv[par][e] accumulates p_m-weighted X in fp32 during the A loads;
// its (par,lh,e) layout IS the A-fragment of the 64x32x64 GEMM against weight_res.
__global__ __launch_bounds__(256, 4) void pconv_kernel(
    const float* __restrict__ in_pc,       // (B, IN_PN, CIN)
    const int*   __restrict__ neighbor_id, // (OUT_PN, M)
    const float* __restrict__ weights,     // (OUT_PN, M, COUT, CIN)
    const float* __restrict__ bias,        // (OUT_PN, COUT)
    const float* __restrict__ p_neighbors, // (OUT_PN, M)
    const float* __restrict__ weight_res,  // (COUT, CIN)
    float*       __restrict__ out)         // (B, OUT_PN, COUT)
{
    const int p    = blockIdx.x;
    const int t    = threadIdx.x;
    const int lane = t & 63;
    const int wv   = t >> 6;
    const int wr   = wv >> 1;       // b-half of C
    const int wc   = wv & 1;        // o-half of C
    const int l32  = lane & 31;
    const int lh   = lane >> 5;     // k-chunk selector

    // ---- block-uniform neighbor ids + normalized residual weights ----
    int   nid[MM];
    float pn[MM];
    float psum = 0.f;
#pragma unroll
    for (int m = 0; m < MM; ++m) {
        nid[m] = neighbor_id[p * MM + m];
        float pv = fabsf(p_neighbors[p * MM + m]);
        pv = (nid[m] != IN_PN) ? pv : 0.f;
        pn[m] = pv;
        psum += pv;
    }
    const float pinv = 1.f / (psum + 1e-8f);
#pragma unroll
    for (int m = 0; m < MM; ++m) pn[m] *= pinv;

    const int brow = wr * 32 + l32;       // A row (batch)
    const int ocol = wc * 32 + l32;       // B col (output channel)

    const float* Abase = in_pc   + (size_t)brow * (IN_PN * CIN) + lh * 8;
    const float* Bbase = weights + (size_t)p * (MM * COUT * CIN) + (size_t)ocol * CIN + lh * 8;

    f32x16 accC, accR;
#pragma unroll
    for (int j = 0; j < 16; ++j) { accC[j] = 0.f; accR[j] = 0.f; }
    float rv[2][8];
#pragma unroll
    for (int i = 0; i < 2; ++i)
#pragma unroll
        for (int e = 0; e < 8; ++e) rv[i][e] = 0.f;

    // ---- main loop: 9 m-steps x 2 K-substeps x 3 split-MFMAs ----
#pragma unroll
    for (int m = 0; m < MM; ++m) {
        const int   n  = nid[m];
        const float pm = pn[m];
        float xa[16], wb[16];
        if (n != IN_PN) {                                  // wave-uniform branch
            const float* a = Abase + (size_t)n * CIN;
            float4 t0 = *(const float4*)(a);
            float4 t1 = *(const float4*)(a + 4);
            float4 t2 = *(const float4*)(a + 16);
            float4 t3 = *(const float4*)(a + 20);
            xa[0]=t0.x;  xa[1]=t0.y;  xa[2]=t0.z;  xa[3]=t0.w;
            xa[4]=t1.x;  xa[5]=t1.y;  xa[6]=t1.z;  xa[7]=t1.w;
            xa[8]=t2.x;  xa[9]=t2.y;  xa[10]=t2.z; xa[11]=t2.w;
            xa[12]=t3.x; xa[13]=t3.y; xa[14]=t3.z; xa[15]=t3.w;
        } else {
#pragma unroll
            for (int e = 0; e < 16; ++e) xa[e] = 0.f;
        }
        {
            const float* bsp = Bbase + m * (COUT * CIN);
            float4 s0 = *(const float4*)(bsp);
            float4 s1 = *(const float4*)(bsp + 4);
            float4 s2 = *(const float4*)(bsp + 16);
            float4 s3 = *(const float4*)(bsp + 20);
            wb[0]=s0.x;  wb[1]=s0.y;  wb[2]=s0.z;  wb[3]=s0.w;
            wb[4]=s1.x;  wb[5]=s1.y;  wb[6]=s1.z;  wb[7]=s1.w;
            wb[8]=s2.x;  wb[9]=s2.y;  wb[10]=s2.z; wb[11]=s2.w;
            wb[12]=s3.x; wb[13]=s3.y; wb[14]=s3.z; wb[15]=s3.w;
        }

#pragma unroll
        for (int par = 0; par < 2; ++par) {
            // residual accumulation rides for free on the A loads
#pragma unroll
            for (int e = 0; e < 8; ++e) rv[par][e] += pm * xa[par * 8 + e];

            u32x4 ah, al, bh, bl;
            split8(&xa[par * 8], ah, al);
            split8(&wb[par * 8], bh, bl);
            accC = __builtin_amdgcn_mfma_f32_32x32x16_bf16(frag(ah), frag(bh), accC, 0, 0, 0);
            accC = __builtin_amdgcn_mfma_f32_32x32x16_bf16(frag(ah), frag(bl), accC, 0, 0, 0);
            accC = __builtin_amdgcn_mfma_f32_32x32x16_bf16(frag(al), frag(bh), accC, 0, 0, 0);
        }
    }

    // ---- residual GEMM: R(64x32) . weight_res^T(32x64), K=32 -> 2 K-steps ----
    {
        const float* wrb = weight_res + (size_t)ocol * CIN + lh * 8;
#pragma unroll
        for (int kk = 0; kk < 2; ++kk) {
            float wb2[8];
            float4 s0 = *(const float4*)(wrb + kk * 16);
            float4 s1 = *(const float4*)(wrb + kk * 16 + 4);
            wb2[0]=s0.x; wb2[1]=s0.y; wb2[2]=s0.z; wb2[3]=s0.w;
            wb2[4]=s1.x; wb2[5]=s1.y; wb2[6]=s1.z; wb2[7]=s1.w;
            u32x4 ah, al, bh, bl;
            split8(&rv[kk][0], ah, al);
            split8(&wb2[0], bh, bl);
            accR = __builtin_amdgcn_mfma_f32_32x32x16_bf16(frag(ah), frag(bh), accR, 0, 0, 0);
            accR = __builtin_amdgcn_mfma_f32_32x32x16_bf16(frag(ah), frag(bl), accR, 0, 0, 0);
            accR = __builtin_amdgcn_mfma_f32_32x32x16_bf16(frag(al), frag(bh), accR, 0, 0, 0);
        }
    }

    // ---- epilogue: bias + elu, combine, direct coalesced stores (128B runs) ----
    const float bv = bias[p * COUT + ocol];
    float* obase = out + (size_t)p * COUT + ocol;
#pragma unroll
    for (int j = 0; j < 16; ++j) {
        const int br = wr * 32 + (j & 3) + 8 * (j >> 2) + 4 * lh;
        float cv = accC[j] + bv;
        cv = (cv > 0.f) ? cv : expm1f(cv);                  // jax.nn.elu
        obase[(size_t)br * (OUT_PN * COUT)] = 0.70710678118654752f * (cv + accR[j]);
    }
}

extern "C" void kernel_launch(void* const* d_in, const int* in_sizes, int n_in,
                              void* d_out, int out_size, void* d_ws, size_t ws_size,
                              hipStream_t stream) {
    const float* in_pc       = (const float*)d_in[0];
    const int*   neighbor_id = (const int*)d_in[1];
    const float* weights     = (const float*)d_in[2];
    const float* bias        = (const float*)d_in[3];
    const float* p_neighbors = (const float*)d_in[4];
    const float* weight_res  = (const float*)d_in[5];
    float*       out         = (float*)d_out;

    pconv_kernel<<<OUT_PN, 256, 0, stream>>>(in_pc, neighbor_id, weights, bias,
                                             p_neighbors, weight_res, out);
}